// Round 11
// baseline (4895.565 us; speedup 1.0000x reference)
//
#include <hip/hip_runtime.h>
#include <math.h>

// POSTagEncoder: expert-routed linear -> 1-layer LSTM (i,f,g,o) -> time max-pool.
// S=8192, D=128, E=48. Output [1,128] fp32.
//
// Round-11: round-8's PASSING structure (compiler-tracked xg loads -- round 10
// proved the inline-asm load scheme corrupts data under register pressure:
// live-range splits insert copies between load-issue and hand-placed vmcnt)
// + round-10's gate-staggered MFMA/epilogue order (numerically identical ops;
// each gate's select/activation threaded between later gates' MFMA groups so
// the transcendental chains issue while the matrix pipe is busy).
// Retained from rounds 5-8 (all verified): 4 waves 1/SIMD, raw lgkmcnt-only
// barrier (1/step), [t][dim][gate] xg layout, distance-2 prefetch, branch-free
// epilogue on all 64 lanes, A-fragments as named v8h vars (AGPR-resident).

#define SEQ   8192
#define DIM   128
#define NGATE 512
#define NEXP  48

typedef _Float16 v8h  __attribute__((ext_vector_type(8)));
typedef float    v4f  __attribute__((ext_vector_type(4)));

__device__ __forceinline__ float sigm_fast(float x) {
    return __fdividef(1.0f, 1.0f + __expf(-x));   // inf-safe both ends
}
__device__ __forceinline__ float tanh_fast(float x) {
    float e = __expf(2.0f * x);
    return 1.0f - __fdividef(2.0f, e + 1.0f);     // +-1 at saturation
}
__device__ __forceinline__ v8h pack8(float4 a, float4 b) {   // RNE converts
    v8h r;
    r[0]=(_Float16)a.x; r[1]=(_Float16)a.y; r[2]=(_Float16)a.z; r[3]=(_Float16)a.w;
    r[4]=(_Float16)b.x; r[5]=(_Float16)b.y; r[6]=(_Float16)b.z; r[7]=(_Float16)b.w;
    return r;
}
// select component (c&1,c&2) from A (half 0) or B (half 1) per (c&4)
__device__ __forceinline__ float selv(v4f A, v4f B, int c) {
    float a01 = (c & 1) ? A[1] : A[0];
    float a23 = (c & 1) ? A[3] : A[2];
    float av  = (c & 2) ? a23 : a01;
    float b01 = (c & 1) ? B[1] : B[0];
    float b23 = (c & 1) ? B[3] : B[2];
    float bv  = (c & 2) ? b23 : b01;
    return (c & 4) ? bv : av;
}

// ---------------------------------------------------------------------------
// K1a: z[s] = W_exp[pos_ids[s]] @ embs[s] + b_exp  -> xg[s*512 + 0..128)
// ---------------------------------------------------------------------------
__global__ __launch_bounds__(64) void expert_gemv(
    const float* __restrict__ embs, const int* __restrict__ pos_ids,
    const float* __restrict__ W_exp, const float* __restrict__ b_exp,
    float* __restrict__ xg)
{
    __shared__ float Wl[DIM * DIM];          // 64KB, rows XOR-swizzled
    const int e     = blockIdx.x % NEXP;
    const int slice = blockIdx.x / NEXP;     // 0..7
    const int tid   = threadIdx.x;           // 0..63

    const float4* Wg = (const float4*)(W_exp + (size_t)e * DIM * DIM);
    #pragma unroll 4
    for (int it = 0; it < 64; ++it) {
        int idx = it * 64 + tid;             // 0..4095 float4s
        int r = idx >> 5, c4 = idx & 31;
        float4 v = Wg[idx];
        *(float4*)&Wl[r * DIM + (((c4 ^ (r & 31))) << 2)] = v;
    }
    const float b0 = b_exp[e * DIM + tid];
    const float b1 = b_exp[e * DIM + 64 + tid];
    __syncthreads();

    const int r0 = tid, r1 = tid + 64;
    const int sw0 = r0 & 31, sw1 = r1 & 31;
    const int sBeg = slice * 1024, sEnd = sBeg + 1024;
    for (int base = sBeg; base < sEnd; base += 64) {
        int pid = pos_ids[base + tid];
        unsigned long long m = __ballot(pid == e);
        while (m) {
            int t = __builtin_ctzll(m);
            m &= m - 1;
            int s = base + t;
            const float4* ev = (const float4*)(embs + (size_t)s * DIM);
            float a0 = b0, a1 = b1;
            #pragma unroll
            for (int j4 = 0; j4 < 32; ++j4) {
                float4 x  = ev[j4];
                float4 w0 = *(const float4*)&Wl[r0 * DIM + ((j4 ^ sw0) << 2)];
                float4 w1 = *(const float4*)&Wl[r1 * DIM + ((j4 ^ sw1) << 2)];
                a0 = fmaf(w0.x,x.x,fmaf(w0.y,x.y,fmaf(w0.z,x.z,fmaf(w0.w,x.w,a0))));
                a1 = fmaf(w1.x,x.x,fmaf(w1.y,x.y,fmaf(w1.z,x.z,fmaf(w1.w,x.w,a1))));
            }
            float* zp = xg + (size_t)s * NGATE;
            zp[tid]      = a0;
            zp[tid + 64] = a1;
        }
    }
}

// ---------------------------------------------------------------------------
// K1b: gates = W_ih @ z + b_ih + b_hh, stored PERMUTED: xg[s][dim*4 + gate]
// ---------------------------------------------------------------------------
__global__ __launch_bounds__(256) void gate_gemm(
    const float* __restrict__ W_ih, const float* __restrict__ b_ih,
    const float* __restrict__ b_hh, float* __restrict__ xg)
{
    __shared__ float zl[32 * DIM];    // 16KB
    __shared__ float Wl[64 * DIM];    // 32KB
    const int tid = threadIdx.x;
    const int s0  = blockIdx.x * 32;

    #pragma unroll
    for (int it = 0; it < 4; ++it) {
        int idx = it * 256 + tid;
        int tok = idx >> 5, c4 = idx & 31;
        float4 v = *(const float4*)(xg + ((size_t)(s0 + tok)) * NGATE + (c4 << 2));
        *(float4*)&zl[tok * DIM + (((c4 ^ (tok & 31))) << 2)] = v;
    }
    __syncthreads();

    const int lane = tid & 63;
    const int tg   = tid >> 6;
    const int swr  = lane & 31;

    for (int ch = 0; ch < 8; ++ch) {
        #pragma unroll
        for (int it = 0; it < 8; ++it) {
            int idx = it * 256 + tid;
            int r = idx >> 5, c4 = idx & 31;
            float4 v = *(const float4*)(W_ih + ((size_t)(ch * 64 + r)) * DIM + (c4 << 2));
            *(float4*)&Wl[r * DIM + ((c4 ^ (r & 31)) << 2)] = v;
        }
        __syncthreads();

        const int row = ch * 64 + lane;      // 0..511
        const float bias = b_ih[row] + b_hh[row];
        float acc[8];
        #pragma unroll
        for (int k = 0; k < 8; ++k) acc[k] = bias;
        #pragma unroll 8
        for (int j4 = 0; j4 < 32; ++j4) {
            float4 w = *(const float4*)&Wl[lane * DIM + ((j4 ^ swr) << 2)];
            #pragma unroll
            for (int k = 0; k < 8; ++k) {
                int tok = tg * 8 + k;
                float4 z = *(const float4*)&zl[tok * DIM + ((j4 ^ (tok & 31)) << 2)];
                acc[k] = fmaf(w.x,z.x,fmaf(w.y,z.y,fmaf(w.z,z.z,fmaf(w.w,z.w,acc[k]))));
            }
        }
        const int pidx = ((row & 127) << 2) + (row >> 7);   // dim*4 + gate
        #pragma unroll
        for (int k = 0; k < 8; ++k) {
            int tok = tg * 8 + k;
            xg[((size_t)(s0 + tok)) * NGATE + pidx] = acc[k];
        }
        __syncthreads();
    }
}

// ---------------------------------------------------------------------------
// K2: MFMA LSTM scan + max-pool. ONE block, 256 threads (4 waves, 1/SIMD).
// Wave wg owns dims [32wg,32wg+32): 8 tiles (gate x half) of 16 rows, K=128 in
// 4 chunks of mfma_f32_16x16x32_f16, gate-staggered issue. Branch-free body.
// ---------------------------------------------------------------------------
__global__ __launch_bounds__(256, 1) void lstm_scan(
    const float* __restrict__ xg, const float* __restrict__ W_hh,
    float* __restrict__ out)
{
    const int T    = threadIdx.x;
    const int wg   = T >> 6;         // wave id: owns dims [32*wg, 32*wg+32)
    const int lane = T & 63;
    const int q    = lane >> 4;      // quad 0..3
    const int c    = lane & 15;      // A row-in-tile; C column
    const int q8   = q * 8;
    // lanes c>=8 mirror c-8 (duplicate identical LDS writes, benign)
    const int d    = wg * 32 + q * 4 + (c & 3) + ((c & 4) ? 16 : 0);

    __shared__ __align__(16) _Float16 hbuf[2][DIM];

    // ---- A-fragments: tile (gate G, half H) rows = G*128 + wg*32 + H*16 + c,
    //      4 K-chunks each; named vars, MFMA-only use -> AGPR-resident ----
#define LOADA(G,H) \
    v8h a##G##H##0, a##G##H##1, a##G##H##2, a##G##H##3; { \
        const float4* p = (const float4*)(W_hh + \
            (size_t)((G) * 128 + wg * 32 + (H) * 16 + c) * DIM) + q * 2; \
        a##G##H##0 = pack8(p[ 0], p[ 1]); \
        a##G##H##1 = pack8(p[ 8], p[ 9]); \
        a##G##H##2 = pack8(p[16], p[17]); \
        a##G##H##3 = pack8(p[24], p[25]); }
    LOADA(0,0) LOADA(0,1) LOADA(1,0) LOADA(1,1)
    LOADA(2,0) LOADA(2,1) LOADA(3,0) LOADA(3,1)
#undef LOADA

    float cst  = 0.0f;
    float hmax = -INFINITY;

    if (T < DIM) hbuf[0][T] = (_Float16)0.0f;   // h_0 = 0
    __syncthreads();                             // once; vmcnt drain harmless

    // per-lane xg column pointer ([t][dim][gate] layout), distance-2 prefetch
    const float* xp = xg + 4 * d;
    float4 X0 = *(const float4*)(xp);            // t = 0
    float4 X1 = *(const float4*)(xp + NGATE);    // t = 1

    const v4f Z4 = {0.0f, 0.0f, 0.0f, 0.0f};

#define MF(G,H,K,B,CIN) __builtin_amdgcn_mfma_f32_16x16x32_f16(a##G##H##K, B, CIN, 0, 0, 0)

    // Gate-staggered step: MFMA groups g -> i -> f -> o(half,half); each gate's
    // select/activation threaded between later groups. Compiler-tracked loads
    // and waitcnts (asm loads proved unsafe in round 10, and neutral in round 9).
#define STEP(XV, tp, bf, nbf) { \
    const v8h B0 = *(const v8h*)&hbuf[bf][ 0 + q8]; \
    const v8h B1 = *(const v8h*)&hbuf[bf][32 + q8]; \
    const v8h B2 = *(const v8h*)&hbuf[bf][64 + q8]; \
    const v8h B3 = *(const v8h*)&hbuf[bf][96 + q8]; \
    const float4 xcur = XV; \
    XV = *(const float4*)(xp + (size_t)(tp) * NGATE); \
    /* --- g gate (G=2): longest downstream chain, issue first --- */ \
    v4f c20 = MF(2,0,0,B0,Z4);   v4f c21 = MF(2,1,0,B0,Z4); \
    c20 = MF(2,0,1,B1,c20);      c21 = MF(2,1,1,B1,c21); \
    c20 = MF(2,0,2,B2,c20);      c21 = MF(2,1,2,B2,c21); \
    c20 = MF(2,0,3,B3,c20);      c21 = MF(2,1,3,B3,c21); \
    /* --- i gate (G=0) --- */ \
    v4f c00 = MF(0,0,0,B0,Z4);   v4f c01 = MF(0,1,0,B0,Z4); \
    c00 = MF(0,0,1,B1,c00);      c01 = MF(0,1,1,B1,c01); \
    c00 = MF(0,0,2,B2,c00);      c01 = MF(0,1,2,B2,c01); \
    c00 = MF(0,0,3,B3,c00);      c01 = MF(0,1,3,B3,c01); \
    /* g epilogue: operands ready (g-MFMAs retired during i group) */ \
    const float pg = selv(c20, c21, c) + xcur.z; \
    const float gv = tanh_fast(pg); \
    /* --- f gate (G=1) --- */ \
    v4f c10 = MF(1,0,0,B0,Z4);   v4f c11 = MF(1,1,0,B0,Z4); \
    c10 = MF(1,0,1,B1,c10);      c11 = MF(1,1,1,B1,c11); \
    c10 = MF(1,0,2,B2,c10);      c11 = MF(1,1,2,B2,c11); \
    c10 = MF(1,0,3,B3,c10);      c11 = MF(1,1,3,B3,c11); \
    /* i epilogue (ready during f group) */ \
    const float pi = selv(c00, c01, c) + xcur.x; \
    const float iv = sigm_fast(pi); \
    const float ig = iv * gv; \
    /* --- o gate (G=3) first half --- */ \
    v4f c30 = MF(3,0,0,B0,Z4);   v4f c31 = MF(3,1,0,B0,Z4); \
    c30 = MF(3,0,1,B1,c30);      c31 = MF(3,1,1,B1,c31); \
    /* f epilogue + cell update (ready during o group) */ \
    const float pf = selv(c10, c11, c) + xcur.y; \
    const float fv = sigm_fast(pf); \
    cst = fmaf(fv, cst, ig); \
    const float tc = tanh_fast(cst); \
    /* --- o gate second half --- */ \
    c30 = MF(3,0,2,B2,c30);      c31 = MF(3,1,2,B2,c31); \
    c30 = MF(3,0,3,B3,c30);      c31 = MF(3,1,3,B3,c31); \
    /* o epilogue: the only work after the last MFMA */ \
    const float po = selv(c30, c31, c) + xcur.w; \
    const float ov = sigm_fast(po); \
    const float h = ov * tc; \
    hmax = fmaxf(hmax, h); \
    hbuf[nbf][d] = (_Float16)h; \
    asm volatile("s_waitcnt lgkmcnt(0)\n\ts_barrier" ::: "memory"); }

    for (int t = 0; t < SEQ; t += 2) {
        const int tp0 = (t + 2 < SEQ) ? t + 2 : SEQ - 1;
        const int tp1 = (t + 3 < SEQ) ? t + 3 : SEQ - 1;
        STEP(X0, tp0, 0, 1)
        STEP(X1, tp1, 1, 0)
    }
#undef STEP
#undef MF

    if (c < 8) out[d] = hmax;   // 32 unique dims per wave -> out[1][128]
}

// ---------------------------------------------------------------------------
extern "C" void kernel_launch(void* const* d_in, const int* in_sizes, int n_in,
                              void* d_out, int out_size, void* d_ws, size_t ws_size,
                              hipStream_t stream)
{
    const float* embs  = (const float*)d_in[0];
    const int*   pos   = (const int*)  d_in[1];
    const float* W_exp = (const float*)d_in[2];
    const float* b_exp = (const float*)d_in[3];
    const float* W_ih  = (const float*)d_in[4];
    const float* W_hh  = (const float*)d_in[5];
    const float* b_ih  = (const float*)d_in[6];
    const float* b_hh  = (const float*)d_in[7];
    float* out = (float*)d_out;
    float* xg  = (float*)d_ws;   // [SEQ][512] fp32 = 16 MB

    expert_gemv<<<dim3(NEXP * 8), 64, 0, stream>>>(embs, pos, W_exp, b_exp, xg);
    gate_gemm  <<<dim3(256), 256, 0, stream>>>(W_ih, b_ih, b_hh, xg);
    lstm_scan  <<<dim3(1), 256, 0, stream>>>(xg, W_hh, out);
}